// Round 9
// baseline (306.617 us; speedup 1.0000x reference)
//
#include <hip/hip_runtime.h>

// GNN: 2x SAGEConv(sum) + global_add_pool + Linear head.
// N=50000 nodes, E=1e6 edges, D=H=64, G=512 graphs, O=16.
//
// R1: CSR gather replaced scatter atomics (2111 -> 606 us).
// R2: sorted-segment pooling replaced atomic pooling (606 -> 395 us).
// R3: binned counting sort for CSR build (395 -> 367 us).
// R4: bf16 feature storage, fp32 accumulate (367 -> 325 us).
// R5: bucket-local degree counting (325 -> 302 us).
// R6: scan-free CSR; grid-stride GEMM regressed (net wash).
// R7: MFMA GEMM, K=128 N=64 bf16 16x16x32 (305 -> 240 us).
// R8: gather was LLC-fill bound (66MB fetch for 6.4MB data: each XCD's L2
// refetches random rows -> 8x duplication). Features now stored PLANAR:
// 8 planes of [NN][16B]; gather block blockIdx%8==q touches only plane q
// (0.8MB) + col (2MB) -> per-XCD working set ~3MB, L2-resident under the
// round-robin block->XCD mapping. h1 written planar by GEMM-1 epilogue;
// GEMMs read root-term chunks from planes. graph_start fused into pool.

namespace {
constexpr int NN = 50000;
constexpr int NE = 1000000;
constexpr int NG = 512;
constexpr int NO = 16;
constexpr int KB = 98;                      // buckets: dst>>9 (512 nodes)
constexpr int BCAP = 16000;                 // slot capacity per bucket
constexpr int EPT = 8;                      // edges per thread (scatter)
constexpr int EPB = 256 * EPT;              // 2048 edges per block
constexpr int SBLK = (NE + EPB - 1) / EPB;  // 489 blocks
constexpr int SEDGE = 12288;                // staged edges in bucket_sort
constexpr int CVT_BLK = (NN + 255) / 256;   // 196 transpose tiles
}

typedef __attribute__((ext_vector_type(8))) short bf16x8;
typedef __attribute__((ext_vector_type(4))) float f32x4;

__device__ __forceinline__ unsigned short f2bf(float f) {
  unsigned u = __float_as_uint(f);
  u += 0x7FFFu + ((u >> 16) & 1u);  // round-to-nearest-even
  return (unsigned short)(u >> 16);
}
__device__ __forceinline__ float bf2f(unsigned short s) {
  return __uint_as_float(((unsigned)s) << 16);
}

// ---------------- CSR build (scan-free bucketed counting sort) -------------

__global__ __launch_bounds__(256) void bucket_scatter(
    const int* __restrict__ ei, int* __restrict__ bcount,
    unsigned int* __restrict__ ebuf) {
  __shared__ int cnt[KB];
  __shared__ int base[KB];
  int t = threadIdx.x;
  if (t < KB) cnt[t] = 0;
  __syncthreads();
  int e0 = blockIdx.x * EPB;
  unsigned int pk[EPT];
#pragma unroll
  for (int i = 0; i < EPT; ++i) {
    int e = e0 + i * 256 + t;
    if (e < NE) {
      unsigned int src = (unsigned int)ei[e];
      unsigned int dst = (unsigned int)ei[NE + e];
      pk[i] = (dst << 16) | src;
      atomicAdd(&cnt[dst >> 9], 1);
    } else {
      pk[i] = 0xFFFFFFFFu;
    }
  }
  __syncthreads();
  if (t < KB) {
    base[t] = t * BCAP + atomicAdd(&bcount[t], cnt[t]);
    cnt[t] = 0;
  }
  __syncthreads();
#pragma unroll
  for (int i = 0; i < EPT; ++i) {
    if (pk[i] != 0xFFFFFFFFu) {
      int b = pk[i] >> 25;  // dst >> 9
      int r = atomicAdd(&cnt[b], 1);
      ebuf[base[b] + r] = pk[i];
    }
  }
}

__global__ __launch_bounds__(512) void bucket_sort(
    const unsigned int* __restrict__ ebuf, const int* __restrict__ bcount,
    unsigned int* __restrict__ meta, unsigned short* __restrict__ col) {
  __shared__ unsigned int se[SEDGE];  // 48 KB edge stage
  __shared__ int cnt[512];
  __shared__ int cur[512];
  int b = blockIdx.x;
  int t = threadIdx.x;
  int n = bcount[b];
  const unsigned int* eb = ebuf + (size_t)b * BCAP;
  cnt[t] = 0;
  __syncthreads();
  for (int j = t; j < n; j += 512) {
    unsigned int p = eb[j];
    if (j < SEDGE) se[j] = p;
    atomicAdd(&cnt[(p >> 16) & 511], 1);
  }
  __syncthreads();
  int deg = cnt[t];
  for (int off = 1; off < 512; off <<= 1) {
    int u = (t >= off) ? cnt[t - off] : 0;
    __syncthreads();
    cnt[t] += u;
    __syncthreads();
  }
  int excl = cnt[t] - deg;
  cur[t] = excl;
  int node = (b << 9) + t;
  if (node < NN) {
    meta[node] = ((unsigned)(b * BCAP + excl) << 11) | (unsigned)deg;
  }
  __syncthreads();
  unsigned short* cb = col + (size_t)b * BCAP;
  for (int j = t; j < n; j += 512) {
    unsigned int p = (j < SEDGE) ? se[j] : eb[j];
    int d = (p >> 16) & 511;
    int pos = atomicAdd(&cur[d], 1);
    cb[pos] = (unsigned short)(p & 0xFFFFu);
  }
}

// ------------- x -> planar bf16 (LDS transpose) + weight prep --------------
// Blocks [0,CVT_BLK): tile of 256 nodes -> 8 planes. Blocks >= CVT_BLK:
// Wt[n][kk] = (kk<64 ? Wl[kk][n] : Wr[kk-64][n]) bf16, both layers.
__global__ __launch_bounds__(256) void cvt_prep(
    const float* __restrict__ x, unsigned short* __restrict__ xp,
    const float* __restrict__ Wl1, const float* __restrict__ Wr1,
    const float* __restrict__ Wl2, const float* __restrict__ Wr2,
    unsigned short* __restrict__ Wt1, unsigned short* __restrict__ Wt2) {
  int b = blockIdx.x;
  int t = threadIdx.x;
  if (b >= CVT_BLK) {
    int id = (b - CVT_BLK) * 256 + t;  // 16384 total
    int half = id >> 13;
    int e = id & 8191;
    int nrow = e >> 7;
    int kk = e & 127;
    const float* Wl = half ? Wl2 : Wl1;
    const float* Wr = half ? Wr2 : Wr1;
    unsigned short* Wt = half ? Wt2 : Wt1;
    float v = (kk < 64) ? Wl[kk * 64 + nrow] : Wr[(kk - 64) * 64 + nrow];
    Wt[nrow * 128 + kk] = f2bf(v);
    return;
  }
  __shared__ unsigned short lds[256 * 66];  // stride 66: conflict-free ph2
  int base = b * 256;
  // Phase 1: coalesced fp32 float4 reads -> bf16 LDS tile
#pragma unroll
  for (int i = 0; i < 16; ++i) {
    int f = i * 256 + t;  // float4 index within tile [0,4096)
    int e = f * 4;
    int nl = e >> 6;  // node-in-tile
    int c = e & 63;
    if (base + nl < NN) {
      float4 v4 = reinterpret_cast<const float4*>(x)[(size_t)base * 16 + f];
      unsigned short* d = lds + nl * 66 + c;
      d[0] = f2bf(v4.x);
      d[1] = f2bf(v4.y);
      d[2] = f2bf(v4.z);
      d[3] = f2bf(v4.w);
    }
  }
  __syncthreads();
  // Phase 2: write planes, 16B coalesced per plane
  int v = base + t;
  if (v >= NN) return;
  const size_t NNS = (size_t)NN * 8;
#pragma unroll
  for (int q = 0; q < 8; ++q) {
    const unsigned short* s = lds + t * 66 + q * 8;
    uint4 u;
    u.x = (unsigned)s[0] | ((unsigned)s[1] << 16);
    u.y = (unsigned)s[2] | ((unsigned)s[3] << 16);
    u.z = (unsigned)s[4] | ((unsigned)s[5] << 16);
    u.w = (unsigned)s[6] | ((unsigned)s[7] << 16);
    *reinterpret_cast<uint4*>(xp + q * NNS + (size_t)v * 8) = u;
  }
}

// ---------------- aggregation (planar gather, no atomics) ----------------
// Block handles plane q = blockIdx%8 (XCD-affine under round-robin
// dispatch) x 256 nodes; 1 thread/node, 16B loads from the 0.8MB plane
// (L2-resident) + the 2MB col window. agg written row-major.
__global__ __launch_bounds__(256) void gather_planar(
    const unsigned short* __restrict__ featp,
    const unsigned int* __restrict__ meta, const unsigned short* __restrict__ col,
    unsigned short* __restrict__ agg) {
  int plane = blockIdx.x & 7;
  int v = (blockIdx.x >> 3) * 256 + threadIdx.x;
  if (v >= NN) return;
  unsigned int m = meta[v];
  int beg = (int)(m >> 11);
  int end = beg + (int)(m & 2047u);
  const uint4* pb =
      reinterpret_cast<const uint4*>(featp + (size_t)plane * NN * 8);
  float acc[8] = {0.f, 0.f, 0.f, 0.f, 0.f, 0.f, 0.f, 0.f};
  for (int j = beg; j < end; ++j) {
    int s = col[j];
    uint4 u = pb[s];
    acc[0] += __uint_as_float(u.x << 16);
    acc[1] += __uint_as_float(u.x & 0xFFFF0000u);
    acc[2] += __uint_as_float(u.y << 16);
    acc[3] += __uint_as_float(u.y & 0xFFFF0000u);
    acc[4] += __uint_as_float(u.z << 16);
    acc[5] += __uint_as_float(u.z & 0xFFFF0000u);
    acc[6] += __uint_as_float(u.w << 16);
    acc[7] += __uint_as_float(u.w & 0xFFFF0000u);
  }
  uint4 o;
  o.x = (unsigned)f2bf(acc[0]) | ((unsigned)f2bf(acc[1]) << 16);
  o.y = (unsigned)f2bf(acc[2]) | ((unsigned)f2bf(acc[3]) << 16);
  o.z = (unsigned)f2bf(acc[4]) | ((unsigned)f2bf(acc[5]) << 16);
  o.w = (unsigned)f2bf(acc[6]) | ((unsigned)f2bf(acc[7]) << 16);
  *reinterpret_cast<uint4*>(agg + (size_t)v * 64 + plane * 8) = o;
}

// ---------------- MFMA GEMM (bf16 in/out, fp32 acc) ----------------
// out[row,:] = relu([A_row | H_row] @ Wt^T + b), K=128, N=64.
// A row-major; H planar (chunks q and q+4 from planes). OUT_PLANAR selects
// epilogue layout (layer 1 -> planar h1; layer 2 -> row-major, in-place).
// Fragment maps verified (learn_hip m89/m120). No LDS; Wt L1-resident.
template <bool OUT_PLANAR>
__global__ __launch_bounds__(256) void sage_mfma(
    const unsigned short* A, const unsigned short* Hp,
    const unsigned short* __restrict__ Wt, const float* __restrict__ bias,
    unsigned short* out) {
  int tid = threadIdx.x;
  int wave = tid >> 6;
  int lane = tid & 63;
  int n = lane & 15;
  int q = lane >> 4;
  long base = ((long)blockIdx.x * 4 + wave) * 16;
  if (base >= NN) return;
  long rowA = base + n;
  if (rowA >= NN) rowA = NN - 1;  // clamped dup read; store predicated

  f32x4 acc[4];
#pragma unroll
  for (int t = 0; t < 4; ++t) {
    float bv = bias[t * 16 + n];
    acc[t][0] = bv;
    acc[t][1] = bv;
    acc[t][2] = bv;
    acc[t][3] = bv;
  }

  const size_t NNS = (size_t)NN * 8;
  const unsigned short* arow = A + rowA * 64;
  const unsigned short* hbase = Hp + rowA * 8;
  bf16x8 af[4];
  af[0] = *(const bf16x8*)(arow + q * 8);                  // k 0..31
  af[1] = *(const bf16x8*)(arow + 32 + q * 8);             // k 32..63
  af[2] = *(const bf16x8*)(hbase + (size_t)q * NNS);       // k 64..95
  af[3] = *(const bf16x8*)(hbase + (size_t)(q + 4) * NNS); // k 96..127

#pragma unroll
  for (int t = 0; t < 4; ++t) {
    const unsigned short* wrow = Wt + (size_t)(t * 16 + n) * 128 + q * 8;
#pragma unroll
    for (int s = 0; s < 4; ++s) {
      bf16x8 bfm = *(const bf16x8*)(wrow + s * 32);
      acc[t] =
          __builtin_amdgcn_mfma_f32_16x16x32_bf16(af[s], bfm, acc[t], 0, 0, 0);
    }
  }

#pragma unroll
  for (int r = 0; r < 4; ++r) {
    long rowc = base + q * 4 + r;
    if (rowc < NN) {
      if (OUT_PLANAR) {
#pragma unroll
        for (int t = 0; t < 4; ++t) {
          int c = t * 16 + n;
          out[(size_t)(c >> 3) * NNS + rowc * 8 + (c & 7)] =
              f2bf(fmaxf(acc[t][r], 0.f));
        }
      } else {
        unsigned short* orow = out + rowc * 64;
#pragma unroll
        for (int t = 0; t < 4; ++t) {
          orow[t * 16 + n] = f2bf(fmaxf(acc[t][r], 0.f));
        }
      }
    }
  }
}

// ---------- pooling (sorted-segment reduction, inline search) + head -------

__global__ __launch_bounds__(64) void pool_head_kernel(
    const unsigned short* __restrict__ h2, const int* __restrict__ batch,
    const float* __restrict__ Wo, const float* __restrict__ bo,
    float* __restrict__ out) {
  __shared__ float sm[64];
  __shared__ int bounds[2];
  int g = blockIdx.x;
  int c = threadIdx.x;
  if (c < 2) {
    int target = g + c;
    int lo = 0, hi = NN;
    while (lo < hi) {
      int mid = (lo + hi) >> 1;
      if (batch[mid] < target)
        lo = mid + 1;
      else
        hi = mid;
    }
    bounds[c] = lo;
  }
  __syncthreads();
  int beg = bounds[0], end = bounds[1];
  float acc = 0.f;
  for (int i = beg; i < end; ++i) acc += bf2f(h2[(size_t)i * 64 + c]);
  sm[c] = acc;
  __syncthreads();
  if (c < NO) {
    float o = bo[c];
#pragma unroll
    for (int k = 0; k < 64; ++k) o += sm[k] * Wo[k * 16 + c];
    out[g * 16 + c] = o;
  }
}

extern "C" void kernel_launch(void* const* d_in, const int* in_sizes, int n_in,
                              void* d_out, int out_size, void* d_ws,
                              size_t ws_size, hipStream_t stream) {
  const float* x = (const float*)d_in[0];
  const int* ei = (const int*)d_in[1];
  const int* batch = (const int*)d_in[2];
  const float* Wl1 = (const float*)d_in[3];
  const float* Wr1 = (const float*)d_in[4];
  const float* b1 = (const float*)d_in[5];
  const float* Wl2 = (const float*)d_in[6];
  const float* Wr2 = (const float*)d_in[7];
  const float* b2 = (const float*)d_in[8];
  const float* Wo = (const float*)d_in[9];
  const float* bo = (const float*)d_in[10];
  float* out = (float*)d_out;

  // Workspace: 16B-aligned big arrays first, then ints.
  unsigned short* xp = (unsigned short*)d_ws;       // planar x  (6.4 MB)
  unsigned short* agg_bf = xp + (size_t)NN * 64;    // row-major (6.4 MB)
  unsigned short* h1p = agg_bf + (size_t)NN * 64;   // planar h1 (6.4 MB)
  unsigned short* col = h1p + (size_t)NN * 64;      // KB*BCAP ushort (3.1MB)
  unsigned short* Wt1 = col + (size_t)KB * BCAP;    // 64*128 bf16
  unsigned short* Wt2 = Wt1 + 64 * 128;             // 64*128 bf16
  unsigned int* meta = (unsigned int*)(Wt2 + 64 * 128);  // NN
  int* bcount = (int*)(meta + NN);                  // KB
  // ebuf (KB*BCAP uint32 = 6.27MB) aliases agg_bf: consumed by bucket_sort
  // before gather first writes agg_bf.
  unsigned int* ebuf = (unsigned int*)agg_bf;

  hipMemsetAsync(bcount, 0, KB * sizeof(int), stream);

  const int gather_blocks = 8 * CVT_BLK;   // 1568: plane = blockIdx % 8
  const int gemm_blocks = (NN + 63) / 64;  // 782: 4 waves x 16 rows

  // x -> planar bf16 + transposed bf16 weights (one launch)
  cvt_prep<<<CVT_BLK + 64, 256, 0, stream>>>(x, xp, Wl1, Wr1, Wl2, Wr2, Wt1,
                                             Wt2);

  // CSR build (scan-free, 2 kernels)
  bucket_scatter<<<SBLK, 256, 0, stream>>>(ei, bcount, ebuf);
  bucket_sort<<<KB, 512, 0, stream>>>(ebuf, bcount, meta, col);

  // Layer 1: gather planes of x -> agg (row-major); GEMM -> h1 (planar)
  gather_planar<<<gather_blocks, 256, 0, stream>>>(xp, meta, col, agg_bf);
  sage_mfma<true><<<gemm_blocks, 256, 0, stream>>>(agg_bf, xp, Wt1, b1, h1p);

  // Layer 2: gather planes of h1 -> agg; GEMM in-place (row-major h2)
  gather_planar<<<gather_blocks, 256, 0, stream>>>(h1p, meta, col, agg_bf);
  sage_mfma<false><<<gemm_blocks, 256, 0, stream>>>(agg_bf, h1p, Wt2, b2,
                                                    agg_bf);

  // Pool (segmented, inline boundary search) + head
  pool_head_kernel<<<NG, 64, 0, stream>>>(agg_bf, batch, Wo, bo, out);
}